// Round 7
// baseline (104.140 us; speedup 1.0000x reference)
//
#include <hip/hip_runtime.h>
#include <hip/hip_bf16.h>

// MultiStepUnitaryGCN — closed-form collapse (validated rounds 2-6, absmax 0.031):
//   conv(h) = cos(t*sqrt(deg)) * (h @ W^T) + b ; neighbors are dead code.
// Round-7: eliminate the x LDS staging round-trip. Phase-1 B-frags (node side)
// are read DIRECTLY from global x (2x float4 + cvt per frag): the staging loop,
// the xt tile and the first __syncthreads are gone; LDS = ht only (16 KB).
// Revert round-6 regressions: cos back in prep, bound 4 now fits (no staging
// temps). Structure otherwise = round 5 (best measured): C[chan][node] operand
// order, in-register phase-2 softmax (shfl_xor 16/32), 1 syncthreads total.
// Frag layout (verified): A/B lane holds 8 contiguous k of row (lane&15),
// k-chunk (lane>>4); C/D row m=(lane>>4)*4+reg, col n=lane&15.

#define NN    50000
#define CIN   128
#define CHID  128
#define COUT  64
#define KNBR  16
#define TM    64      // nodes per block
#define BLOCK 256

typedef unsigned short u16;
typedef unsigned int   u32;
typedef __attribute__((ext_vector_type(8))) short bf16x8;
typedef __attribute__((ext_vector_type(4))) float f32x4;

__device__ __forceinline__ u16 f2bf(float f) {
    __hip_bfloat16 h = __float2bfloat16(f);
    return *reinterpret_cast<u16*>(&h);
}
__device__ __forceinline__ uint4 pack8u(const float* __restrict__ p) {
    float tmp[8];
    *(float4*)(tmp)     = *(const float4*)(p);
    *(float4*)(tmp + 4) = *(const float4*)(p + 4);
    union { u16 h[8]; uint4 v; } r;
    #pragma unroll
    for (int i = 0; i < 8; ++i) r.h[i] = f2bf(tmp[i]);
    return r.v;
}
// 8 consecutive f32 (global) -> bf16x8 fragment in registers
__device__ __forceinline__ bf16x8 pack8f(const float* __restrict__ p) {
    float tmp[8];
    *(float4*)(tmp)     = *(const float4*)(p);
    *(float4*)(tmp + 4) = *(const float4*)(p + 4);
    union { short s[8]; bf16x8 v; } r;
    #pragma unroll
    for (int i = 0; i < 8; ++i) r.s[i] = (short)f2bf(tmp[i]);
    return r.v;
}

// XOR swizzle on 16B groups: group g of row r stored at (g ^ (r&15)).
__device__ __forceinline__ int sw(int row, int g) { return (g ^ (row & 15)) << 3; }

// d_ws layout:
//   [0, 48K): weight frag image (uint4 = 8 bf16):
//     W1 group (c,kg) -> idx kg*128 + c         (c<128, kg=k/8<16)
//     W2 group (c,kg) -> idx 2048 + kg*64 + c   (c<64)
//   [64K, ...): c1[50000] f32, c2[50000] f32.
#define WS_CC_OFF 65536
#define CC_BLOCKS 196   // ceil(50000/256)

// ---- fused prep: blocks [0,196) deg->cos ; blocks [196,208) W pack ----
__global__ void prep(const float* __restrict__ w1g,
                     const float* __restrict__ w2g,
                     const int* __restrict__ maskg,
                     uint4* __restrict__ wimg,
                     float* __restrict__ cc)
{
    int b = blockIdx.x;
    if (b < CC_BLOCKS) {
        int n = b * BLOCK + threadIdx.x;
        if (n < NN) {
            const int4* mp = (const int4*)(maskg + (size_t)n * KNBR);
            int deg = 0;
            #pragma unroll
            for (int j = 0; j < 4; ++j) {
                int4 v = mp[j];
                deg += (v.x != 0) + (v.y != 0) + (v.z != 0) + (v.w != 0);
            }
            float sd = sqrtf((float)deg);
            cc[n]      = cosf(sd);          // T1 = 1.0
            cc[NN + n] = cosf(0.5f * sd);   // T2 = 0.5
        }
    } else {
        int gid = (b - CC_BLOCKS) * BLOCK + threadIdx.x;   // 0..3071
        if (gid < 2048) {                 // W1: 128 c x 16 kg
            int c = gid >> 4, kg = gid & 15;
            wimg[kg * 128 + c] = pack8u(w1g + c * CIN + kg * 8);
        } else if (gid < 3072) {          // W2: 64 c x 16 kg
            int g2 = gid - 2048;
            int c = g2 >> 4, kg = g2 & 15;
            wimg[2048 + kg * 64 + c] = pack8u(w2g + c * CHID + kg * 8);
        }
    }
}

__global__ __launch_bounds__(BLOCK, 4)
void gcn_mfma(const float* __restrict__ xg,
              const uint4* __restrict__ wimg,
              const float* __restrict__ cc,
              const float* __restrict__ b1g,
              const float* __restrict__ b2g,
              float* __restrict__ out)
{
    __shared__ __align__(16) u16 ht[TM * CHID];   // 16 KB, swizzled bf16

    const int t  = threadIdx.x;
    const int w  = t >> 6;        // wave 0..3
    const int L  = t & 63;
    const int q  = L >> 4;        // quad 0..3
    const int lm = L & 15;
    const int m0 = blockIdx.x * TM;

    // per-lane node rows for the 4 N-tiles (clamped: OOB lanes read row NN-1,
    // results discarded by the store guard; avoids faults and NaN)
    int rowc[4];
    float c1n[4];
    #pragma unroll
    for (int nt = 0; nt < 4; ++nt) {
        int gn = m0 + nt * 16 + lm;
        int rc = gn < NN ? gn : NN - 1;
        rowc[nt] = rc;
        c1n[nt] = (gn < NN) ? cc[gn] : 0.f;
    }

    // ---- W1 A-frags: chans (2w+mt)*16+lm, k-chunk kg=k4*4+q ----
    bf16x8 w1f[2][4];
    #pragma unroll
    for (int mt = 0; mt < 2; ++mt) {
        int c = (2 * w + mt) * 16 + lm;
        #pragma unroll
        for (int k4 = 0; k4 < 4; ++k4)
            w1f[mt][k4] = *(const bf16x8*)&wimg[(k4 * 4 + q) * 128 + c];
    }

    // ---- phase 1: C1[chan][node] = W1 * x^T; x frags direct from global ----
    f32x4 acc[2][4];
    #pragma unroll
    for (int mt = 0; mt < 2; ++mt)
        #pragma unroll
        for (int nt = 0; nt < 4; ++nt)
            acc[mt][nt] = (f32x4){0.f, 0.f, 0.f, 0.f};

    #pragma unroll
    for (int k4 = 0; k4 < 4; ++k4) {
        bf16x8 xf[4];
        #pragma unroll
        for (int nt = 0; nt < 4; ++nt)
            xf[nt] = pack8f(xg + (size_t)rowc[nt] * CIN + k4 * 32 + q * 8);
        #pragma unroll
        for (int mt = 0; mt < 2; ++mt)
            #pragma unroll
            for (int nt = 0; nt < 4; ++nt)
                acc[mt][nt] = __builtin_amdgcn_mfma_f32_16x16x32_bf16(
                    w1f[mt][k4], xf[nt], acc[mt][nt], 0, 0, 0);
    }

    // h = relu(c1*acc + b1): reg quad = 4 consecutive chans -> one b64 per tile
    #pragma unroll
    for (int mt = 0; mt < 2; ++mt) {
        int chan0 = (2 * w + mt) * 16 + q * 4;
        float4 bb = *(const float4*)(b1g + chan0);
        #pragma unroll
        for (int nt = 0; nt < 4; ++nt) {
            int node = nt * 16 + lm;
            float c1 = c1n[nt];
            u16 h0 = f2bf(fmaxf(fmaf(c1, acc[mt][nt][0], bb.x), 0.f));
            u16 h1 = f2bf(fmaxf(fmaf(c1, acc[mt][nt][1], bb.y), 0.f));
            u16 h2 = f2bf(fmaxf(fmaf(c1, acc[mt][nt][2], bb.z), 0.f));
            u16 h3 = f2bf(fmaxf(fmaf(c1, acc[mt][nt][3], bb.w), 0.f));
            uint2 pkt = make_uint2(((u32)h0) | ((u32)h1 << 16),
                                   ((u32)h2) | ((u32)h3 << 16));
            *(uint2*)&ht[node * CHID + sw(node, chan0 >> 3) + (chan0 & 7)] = pkt;
        }
    }
    __syncthreads();

    // ---- phase 2: wave w owns nodes [16w,16w+16); all 4 chan M-tiles ----
    const int node = 16 * w + lm;
    const int gn   = m0 + node;

    bf16x8 hf[4];
    #pragma unroll
    for (int k4 = 0; k4 < 4; ++k4)
        hf[k4] = *(const bf16x8*)&ht[node * CHID + sw(node, k4 * 4 + q)];

    float o[4][4];   // [mt][r]: chan = mt*16 + q*4 + r, this lane's node
    float c2 = (gn < NN) ? cc[NN + gn] : 0.f;
    #pragma unroll
    for (int mt = 0; mt < 4; ++mt) {
        bf16x8 w2f[4];
        #pragma unroll
        for (int k4 = 0; k4 < 4; ++k4)
            w2f[k4] = *(const bf16x8*)&wimg[2048 + (k4 * 4 + q) * 64 + (mt * 16 + lm)];
        f32x4 a2 = (f32x4){0.f, 0.f, 0.f, 0.f};
        #pragma unroll
        for (int k4 = 0; k4 < 4; ++k4)
            a2 = __builtin_amdgcn_mfma_f32_16x16x32_bf16(w2f[k4], hf[k4], a2, 0, 0, 0);
        float4 bb = *(const float4*)(b2g + mt * 16 + q * 4);
        o[mt][0] = fmaf(c2, a2[0], bb.x);
        o[mt][1] = fmaf(c2, a2[1], bb.y);
        o[mt][2] = fmaf(c2, a2[2], bb.z);
        o[mt][3] = fmaf(c2, a2[3], bb.w);
    }

    // ---- in-register log-softmax over 64 chans (16 in-lane x 4 quads) ----
    float M = -1e30f;
    #pragma unroll
    for (int mt = 0; mt < 4; ++mt)
        #pragma unroll
        for (int r = 0; r < 4; ++r) M = fmaxf(M, o[mt][r]);
    M = fmaxf(M, __shfl_xor(M, 16));
    M = fmaxf(M, __shfl_xor(M, 32));

    float S = 0.f;
    #pragma unroll
    for (int mt = 0; mt < 4; ++mt)
        #pragma unroll
        for (int r = 0; r < 4; ++r) S += __expf(o[mt][r] - M);
    S += __shfl_xor(S, 16);
    S += __shfl_xor(S, 32);
    float lse = M + __logf(S);

    if (gn < NN) {
        #pragma unroll
        for (int mt = 0; mt < 4; ++mt) {
            float4 v;
            v.x = o[mt][0] - lse;
            v.y = o[mt][1] - lse;
            v.z = o[mt][2] - lse;
            v.w = o[mt][3] - lse;
            *(float4*)(out + (size_t)gn * COUT + mt * 16 + q * 4) = v;
        }
    }
}

extern "C" void kernel_launch(void* const* d_in, const int* in_sizes, int n_in,
                              void* d_out, int out_size, void* d_ws, size_t ws_size,
                              hipStream_t stream) {
    const float* x   = (const float*)d_in[0];
    // d_in[1] = neighbors — mathematically irrelevant (Re(G[0,j>=1]) == 0)
    const int* mask  = (const int*)d_in[2];
    const float* w1  = (const float*)d_in[3];
    const float* b1  = (const float*)d_in[4];
    const float* w2  = (const float*)d_in[5];
    const float* b2  = (const float*)d_in[6];
    float* out = (float*)d_out;

    uint4* wimg = (uint4*)d_ws;
    float* cc   = (float*)((char*)d_ws + WS_CC_OFF);

    hipLaunchKernelGGL(prep, dim3(CC_BLOCKS + 12), dim3(BLOCK), 0, stream,
                       w1, w2, mask, wimg, cc);

    int grid = (NN + TM - 1) / TM;   // 782
    hipLaunchKernelGGL(gcn_mfma, dim3(grid), dim3(BLOCK), 0, stream,
                       x, wimg, cc, b1, b2, out);
}

// Round 8
// 95.497 us; speedup vs baseline: 1.0905x; 1.0905x over previous
//
#include <hip/hip_runtime.h>
#include <hip/hip_bf16.h>

// MultiStepUnitaryGCN — closed-form collapse (validated rounds 2-7, absmax 0.031):
//   conv(h) = cos(t*sqrt(deg)) * (h @ W^T) + b ; neighbors are dead code.
// Round-8: base = round 5 (best measured, 92.1). Single change: deg->cos moved
// into the main kernel LANE-PARALLEL (each lane loads the 4 mask rows of its
// own N-tile nodes, coalesced, issued with the W1 frag loads; no LDS, no
// barrier dependency — avoids R6's wave-0-before-barrier serialization).
// Prep shrinks 208 -> 12 blocks (W frag pack only); cc ws round-trip deleted.
// R7 lesson: x staging through LDS is mandatory (direct global frags +12us).
// Frag layout (verified): A/B lane holds 8 contiguous k of row (lane&15),
// k-chunk (lane>>4); C/D row m=(lane>>4)*4+reg, col n=lane&15.

#define NN    50000
#define CIN   128
#define CHID  128
#define COUT  64
#define KNBR  16
#define TM    64      // nodes per block
#define BLOCK 256

typedef unsigned short u16;
typedef unsigned int   u32;
typedef __attribute__((ext_vector_type(8))) short bf16x8;
typedef __attribute__((ext_vector_type(4))) float f32x4;

__device__ __forceinline__ u16 f2bf(float f) {
    __hip_bfloat16 h = __float2bfloat16(f);
    return *reinterpret_cast<u16*>(&h);
}
__device__ __forceinline__ uint4 pack8u(const float* __restrict__ p) {
    float tmp[8];
    *(float4*)(tmp)     = *(const float4*)(p);
    *(float4*)(tmp + 4) = *(const float4*)(p + 4);
    union { u16 h[8]; uint4 v; } r;
    #pragma unroll
    for (int i = 0; i < 8; ++i) r.h[i] = f2bf(tmp[i]);
    return r.v;
}

// XOR swizzle on 16B groups: group g of row r stored at (g ^ (r&15)).
__device__ __forceinline__ int sw(int row, int g) { return (g ^ (row & 15)) << 3; }

// d_ws layout: [0, 48K): weight frag image (uint4 = 8 bf16):
//   W1 group (c,kg) -> idx kg*128 + c         (c<128, kg=k/8<16)
//   W2 group (c,kg) -> idx 2048 + kg*64 + c   (c<64)

// ---- prep: pack W1/W2 f32 -> bf16 frag image (12 blocks x 256 = 3072 groups) ----
__global__ void wprep(const float* __restrict__ w1g,
                      const float* __restrict__ w2g,
                      uint4* __restrict__ wimg)
{
    int gid = blockIdx.x * BLOCK + threadIdx.x;
    if (gid < 2048) {                 // W1: 128 c x 16 kg
        int c = gid >> 4, kg = gid & 15;
        wimg[kg * 128 + c] = pack8u(w1g + c * CIN + kg * 8);
    } else {                          // W2: 64 c x 16 kg
        int g2 = gid - 2048;
        int c = g2 >> 4, kg = g2 & 15;
        wimg[2048 + kg * 64 + c] = pack8u(w2g + c * CHID + kg * 8);
    }
}

__global__ __launch_bounds__(BLOCK, 3)
void gcn_mfma(const float* __restrict__ xg,
              const uint4* __restrict__ wimg,
              const int* __restrict__ maskg,
              const float* __restrict__ b1g,
              const float* __restrict__ b2g,
              float* __restrict__ out)
{
    __shared__ __align__(16) u16 xt[TM * CIN];    // 16 KB, swizzled bf16
    __shared__ __align__(16) u16 ht[TM * CHID];   // 16 KB, swizzled bf16

    const int t  = threadIdx.x;
    const int w  = t >> 6;        // wave 0..3
    const int L  = t & 63;
    const int q  = L >> 4;        // quad 0..3
    const int lm = L & 15;
    const int m0 = blockIdx.x * TM;

    // ---- stage x tile: 64 rows x 16 groups (8 f32 -> 8 bf16) ----
    #pragma unroll
    for (int i = 0; i < 4; ++i) {
        int c = t + i * BLOCK;
        int row = c >> 4, g = c & 15;
        int gn = m0 + row;
        uint4 v = make_uint4(0u, 0u, 0u, 0u);
        if (gn < NN) v = pack8u(xg + (size_t)gn * CIN + (g << 3));
        *(uint4*)&xt[row * CIN + sw(row, g)] = v;
    }

    // ---- W1 A-frags: chans (2w+mt)*16+lm, k-chunk kg=k4*4+q ----
    bf16x8 w1f[2][4];
    #pragma unroll
    for (int mt = 0; mt < 2; ++mt) {
        int c = (2 * w + mt) * 16 + lm;
        #pragma unroll
        for (int k4 = 0; k4 < 4; ++k4)
            w1f[mt][k4] = *(const bf16x8*)&wimg[(k4 * 4 + q) * 128 + c];
    }

    // ---- lane-parallel deg -> cos for this lane's 4 N-tile nodes ----
    // Node of N-tile nt for this lane = m0 + nt*16 + lm (phase-2 node = nt==w).
    // Coalesced: for fixed (nt,j), lanes 0..15 read consecutive 64B mask rows.
    // No barrier involvement; transcendentals overlap other waves' MFMA.
    float c1n[4];
    float c2 = 0.f;
    {
        int4 mrow[16];
        #pragma unroll
        for (int nt = 0; nt < 4; ++nt) {
            int gn = m0 + nt * 16 + lm;
            int rc = gn < NN ? gn : NN - 1;   // clamp: results discarded by store guard
            const int4* mp = (const int4*)(maskg + (size_t)rc * KNBR);
            #pragma unroll
            for (int j = 0; j < 4; ++j) mrow[nt * 4 + j] = mp[j];
        }
        float sdw = 0.f;
        #pragma unroll
        for (int nt = 0; nt < 4; ++nt) {
            int deg = 0;
            #pragma unroll
            for (int j = 0; j < 4; ++j) {
                int4 v = mrow[nt * 4 + j];
                deg += (v.x != 0) + (v.y != 0) + (v.z != 0) + (v.w != 0);
            }
            float sd = sqrtf((float)deg);
            c1n[nt] = cosf(sd);          // T1 = 1.0
            if (nt == w) sdw = sd;
        }
        c2 = cosf(0.5f * sdw);           // T2 = 0.5, this lane's phase-2 node
    }
    __syncthreads();

    // ---- phase 1: C1[chan][node] = W1 * x^T  (2 M-tiles x 4 N-tiles) ----
    f32x4 acc[2][4];
    #pragma unroll
    for (int mt = 0; mt < 2; ++mt)
        #pragma unroll
        for (int nt = 0; nt < 4; ++nt)
            acc[mt][nt] = (f32x4){0.f, 0.f, 0.f, 0.f};

    #pragma unroll
    for (int k4 = 0; k4 < 4; ++k4) {
        bf16x8 xf[4];
        #pragma unroll
        for (int nt = 0; nt < 4; ++nt) {
            int r = nt * 16 + lm;
            xf[nt] = *(const bf16x8*)&xt[r * CIN + sw(r, k4 * 4 + q)];
        }
        #pragma unroll
        for (int mt = 0; mt < 2; ++mt)
            #pragma unroll
            for (int nt = 0; nt < 4; ++nt)
                acc[mt][nt] = __builtin_amdgcn_mfma_f32_16x16x32_bf16(
                    w1f[mt][k4], xf[nt], acc[mt][nt], 0, 0, 0);
    }

    // h = relu(c1*acc + b1): reg quad = 4 consecutive chans -> one b64 per tile
    #pragma unroll
    for (int mt = 0; mt < 2; ++mt) {
        int chan0 = (2 * w + mt) * 16 + q * 4;
        float4 bb = *(const float4*)(b1g + chan0);
        #pragma unroll
        for (int nt = 0; nt < 4; ++nt) {
            int node = nt * 16 + lm;
            float c1 = c1n[nt];
            u16 h0 = f2bf(fmaxf(fmaf(c1, acc[mt][nt][0], bb.x), 0.f));
            u16 h1 = f2bf(fmaxf(fmaf(c1, acc[mt][nt][1], bb.y), 0.f));
            u16 h2 = f2bf(fmaxf(fmaf(c1, acc[mt][nt][2], bb.z), 0.f));
            u16 h3 = f2bf(fmaxf(fmaf(c1, acc[mt][nt][3], bb.w), 0.f));
            uint2 pkt = make_uint2(((u32)h0) | ((u32)h1 << 16),
                                   ((u32)h2) | ((u32)h3 << 16));
            *(uint2*)&ht[node * CHID + sw(node, chan0 >> 3) + (chan0 & 7)] = pkt;
        }
    }
    __syncthreads();

    // ---- phase 2: wave w owns nodes [16w,16w+16); all 4 chan M-tiles ----
    const int node = 16 * w + lm;
    const int gn   = m0 + node;

    bf16x8 hf[4];
    #pragma unroll
    for (int k4 = 0; k4 < 4; ++k4)
        hf[k4] = *(const bf16x8*)&ht[node * CHID + sw(node, k4 * 4 + q)];

    float o[4][4];   // [mt][r]: chan = mt*16 + q*4 + r, this lane's node
    #pragma unroll
    for (int mt = 0; mt < 4; ++mt) {
        bf16x8 w2f[4];
        #pragma unroll
        for (int k4 = 0; k4 < 4; ++k4)
            w2f[k4] = *(const bf16x8*)&wimg[2048 + (k4 * 4 + q) * 64 + (mt * 16 + lm)];
        f32x4 a2 = (f32x4){0.f, 0.f, 0.f, 0.f};
        #pragma unroll
        for (int k4 = 0; k4 < 4; ++k4)
            a2 = __builtin_amdgcn_mfma_f32_16x16x32_bf16(w2f[k4], hf[k4], a2, 0, 0, 0);
        float4 bb = *(const float4*)(b2g + mt * 16 + q * 4);
        o[mt][0] = fmaf(c2, a2[0], bb.x);
        o[mt][1] = fmaf(c2, a2[1], bb.y);
        o[mt][2] = fmaf(c2, a2[2], bb.z);
        o[mt][3] = fmaf(c2, a2[3], bb.w);
    }

    // ---- in-register log-softmax over 64 chans (16 in-lane x 4 quads) ----
    float M = -1e30f;
    #pragma unroll
    for (int mt = 0; mt < 4; ++mt)
        #pragma unroll
        for (int r = 0; r < 4; ++r) M = fmaxf(M, o[mt][r]);
    M = fmaxf(M, __shfl_xor(M, 16));
    M = fmaxf(M, __shfl_xor(M, 32));

    float S = 0.f;
    #pragma unroll
    for (int mt = 0; mt < 4; ++mt)
        #pragma unroll
        for (int r = 0; r < 4; ++r) S += __expf(o[mt][r] - M);
    S += __shfl_xor(S, 16);
    S += __shfl_xor(S, 32);
    float lse = M + __logf(S);

    if (gn < NN) {
        #pragma unroll
        for (int mt = 0; mt < 4; ++mt) {
            float4 v;
            v.x = o[mt][0] - lse;
            v.y = o[mt][1] - lse;
            v.z = o[mt][2] - lse;
            v.w = o[mt][3] - lse;
            *(float4*)(out + (size_t)gn * COUT + mt * 16 + q * 4) = v;
        }
    }
}

extern "C" void kernel_launch(void* const* d_in, const int* in_sizes, int n_in,
                              void* d_out, int out_size, void* d_ws, size_t ws_size,
                              hipStream_t stream) {
    const float* x   = (const float*)d_in[0];
    // d_in[1] = neighbors — mathematically irrelevant (Re(G[0,j>=1]) == 0)
    const int* mask  = (const int*)d_in[2];
    const float* w1  = (const float*)d_in[3];
    const float* b1  = (const float*)d_in[4];
    const float* w2  = (const float*)d_in[5];
    const float* b2  = (const float*)d_in[6];
    float* out = (float*)d_out;

    uint4* wimg = (uint4*)d_ws;

    hipLaunchKernelGGL(wprep, dim3(12), dim3(BLOCK), 0, stream, w1, w2, wimg);

    int grid = (NN + TM - 1) / TM;   // 782
    hipLaunchKernelGGL(gcn_mfma, dim3(grid), dim3(BLOCK), 0, stream,
                       x, wimg, mask, b1, b2, out);
}

// Round 9
// 91.982 us; speedup vs baseline: 1.1322x; 1.0382x over previous
//
#include <hip/hip_runtime.h>
#include <hip/hip_bf16.h>

// MultiStepUnitaryGCN — closed-form collapse (validated rounds 2-8, absmax 0.031):
//   conv(h) = cos(t*sqrt(deg)) * (h @ W^T) + b ; neighbors are dead code.
// Round-9: base = round 5 (best measured, 92.1). Single change: deg->cos in
// main via MINIMAL-footprint path — 1 coalesced int4/thread (node=t>>2,
// quarter=t&3), deg reduced by 2 shfl_xor, one lane/node does __cosf into
// c1v/c2v LDS before the existing staging barrier. No mrow[16] register spike
// (R8's bug: 64 transient VGPRs + 4x redundant loads), no wave-0 serialization
// (R6's bug). Prep = 12-block W-pack only; cc ws round-trip deleted.
// R7 lesson: x staging through LDS is mandatory (direct global frags +12us).
// Frag layout (verified): A/B lane holds 8 contiguous k of row (lane&15),
// k-chunk (lane>>4); C/D row m=(lane>>4)*4+reg, col n=lane&15.

#define NN    50000
#define CIN   128
#define CHID  128
#define COUT  64
#define KNBR  16
#define TM    64      // nodes per block
#define BLOCK 256

typedef unsigned short u16;
typedef unsigned int   u32;
typedef __attribute__((ext_vector_type(8))) short bf16x8;
typedef __attribute__((ext_vector_type(4))) float f32x4;

__device__ __forceinline__ u16 f2bf(float f) {
    __hip_bfloat16 h = __float2bfloat16(f);
    return *reinterpret_cast<u16*>(&h);
}
__device__ __forceinline__ uint4 pack8u(const float* __restrict__ p) {
    float tmp[8];
    *(float4*)(tmp)     = *(const float4*)(p);
    *(float4*)(tmp + 4) = *(const float4*)(p + 4);
    union { u16 h[8]; uint4 v; } r;
    #pragma unroll
    for (int i = 0; i < 8; ++i) r.h[i] = f2bf(tmp[i]);
    return r.v;
}

// XOR swizzle on 16B groups: group g of row r stored at (g ^ (r&15)).
__device__ __forceinline__ int sw(int row, int g) { return (g ^ (row & 15)) << 3; }

// d_ws layout: [0, 48K): weight frag image (uint4 = 8 bf16):
//   W1 group (c,kg) -> idx kg*128 + c         (c<128, kg=k/8<16)
//   W2 group (c,kg) -> idx 2048 + kg*64 + c   (c<64)

// ---- prep: pack W1/W2 f32 -> bf16 frag image (12 blocks x 256 = 3072 groups) ----
__global__ void wprep(const float* __restrict__ w1g,
                      const float* __restrict__ w2g,
                      uint4* __restrict__ wimg)
{
    int gid = blockIdx.x * BLOCK + threadIdx.x;
    if (gid < 2048) {                 // W1: 128 c x 16 kg
        int c = gid >> 4, kg = gid & 15;
        wimg[kg * 128 + c] = pack8u(w1g + c * CIN + kg * 8);
    } else {                          // W2: 64 c x 16 kg
        int g2 = gid - 2048;
        int c = g2 >> 4, kg = g2 & 15;
        wimg[2048 + kg * 64 + c] = pack8u(w2g + c * CHID + kg * 8);
    }
}

__global__ __launch_bounds__(BLOCK, 3)
void gcn_mfma(const float* __restrict__ xg,
              const uint4* __restrict__ wimg,
              const int* __restrict__ maskg,
              const float* __restrict__ b1g,
              const float* __restrict__ b2g,
              float* __restrict__ out)
{
    __shared__ __align__(16) u16 xt[TM * CIN];    // 16 KB, swizzled bf16
    __shared__ __align__(16) u16 ht[TM * CHID];   // 16 KB, swizzled bf16
    __shared__ float c1v[TM], c2v[TM];

    const int t  = threadIdx.x;
    const int w  = t >> 6;        // wave 0..3
    const int L  = t & 63;
    const int q  = L >> 4;        // quad 0..3
    const int lm = L & 15;
    const int m0 = blockIdx.x * TM;

    // ---- minimal deg->cos: thread t covers quarter (t&3) of node (t>>2) ----
    // One coalesced int4/thread (4 KB/block total); deg via 2 shfl_xor within
    // the 4-lane group; one lane/node does 2 __cosf. Writes complete before
    // the staging barrier below — no extra synchronization.
    {
        int nodeL = t >> 2;                       // 0..63
        int gn = m0 + nodeL;
        int rc = gn < NN ? gn : NN - 1;           // clamp; OOB results discarded
        const int4* mp = (const int4*)(maskg + (size_t)rc * KNBR);
        int4 v = mp[t & 3];
        int deg = (v.x != 0) + (v.y != 0) + (v.z != 0) + (v.w != 0);
        deg += __shfl_xor(deg, 1);
        deg += __shfl_xor(deg, 2);
        if ((t & 3) == 0) {
            float sd = __fsqrt_rn((float)deg);
            c1v[nodeL] = __cosf(sd);          // T1 = 1.0
            c2v[nodeL] = __cosf(0.5f * sd);   // T2 = 0.5
        }
    }

    // ---- stage x tile: 64 rows x 16 groups (8 f32 -> 8 bf16) ----
    #pragma unroll
    for (int i = 0; i < 4; ++i) {
        int c = t + i * BLOCK;
        int row = c >> 4, g = c & 15;
        int gn = m0 + row;
        uint4 v = make_uint4(0u, 0u, 0u, 0u);
        if (gn < NN) v = pack8u(xg + (size_t)gn * CIN + (g << 3));
        *(uint4*)&xt[row * CIN + sw(row, g)] = v;
    }

    // ---- W1 A-frags: chans (2w+mt)*16+lm, k-chunk kg=k4*4+q ----
    bf16x8 w1f[2][4];
    #pragma unroll
    for (int mt = 0; mt < 2; ++mt) {
        int c = (2 * w + mt) * 16 + lm;
        #pragma unroll
        for (int k4 = 0; k4 < 4; ++k4)
            w1f[mt][k4] = *(const bf16x8*)&wimg[(k4 * 4 + q) * 128 + c];
    }
    __syncthreads();

    float c1n[4];
    #pragma unroll
    for (int nt = 0; nt < 4; ++nt) c1n[nt] = c1v[nt * 16 + lm];

    // ---- phase 1: C1[chan][node] = W1 * x^T  (2 M-tiles x 4 N-tiles) ----
    f32x4 acc[2][4];
    #pragma unroll
    for (int mt = 0; mt < 2; ++mt)
        #pragma unroll
        for (int nt = 0; nt < 4; ++nt)
            acc[mt][nt] = (f32x4){0.f, 0.f, 0.f, 0.f};

    #pragma unroll
    for (int k4 = 0; k4 < 4; ++k4) {
        bf16x8 xf[4];
        #pragma unroll
        for (int nt = 0; nt < 4; ++nt) {
            int r = nt * 16 + lm;
            xf[nt] = *(const bf16x8*)&xt[r * CIN + sw(r, k4 * 4 + q)];
        }
        #pragma unroll
        for (int mt = 0; mt < 2; ++mt)
            #pragma unroll
            for (int nt = 0; nt < 4; ++nt)
                acc[mt][nt] = __builtin_amdgcn_mfma_f32_16x16x32_bf16(
                    w1f[mt][k4], xf[nt], acc[mt][nt], 0, 0, 0);
    }

    // h = relu(c1*acc + b1): reg quad = 4 consecutive chans -> one b64 per tile
    #pragma unroll
    for (int mt = 0; mt < 2; ++mt) {
        int chan0 = (2 * w + mt) * 16 + q * 4;
        float4 bb = *(const float4*)(b1g + chan0);
        #pragma unroll
        for (int nt = 0; nt < 4; ++nt) {
            int node = nt * 16 + lm;
            float c1 = c1n[nt];
            u16 h0 = f2bf(fmaxf(fmaf(c1, acc[mt][nt][0], bb.x), 0.f));
            u16 h1 = f2bf(fmaxf(fmaf(c1, acc[mt][nt][1], bb.y), 0.f));
            u16 h2 = f2bf(fmaxf(fmaf(c1, acc[mt][nt][2], bb.z), 0.f));
            u16 h3 = f2bf(fmaxf(fmaf(c1, acc[mt][nt][3], bb.w), 0.f));
            uint2 pkt = make_uint2(((u32)h0) | ((u32)h1 << 16),
                                   ((u32)h2) | ((u32)h3 << 16));
            *(uint2*)&ht[node * CHID + sw(node, chan0 >> 3) + (chan0 & 7)] = pkt;
        }
    }
    __syncthreads();

    // ---- phase 2: wave w owns nodes [16w,16w+16); all 4 chan M-tiles ----
    const int node = 16 * w + lm;
    const int gn   = m0 + node;

    bf16x8 hf[4];
    #pragma unroll
    for (int k4 = 0; k4 < 4; ++k4)
        hf[k4] = *(const bf16x8*)&ht[node * CHID + sw(node, k4 * 4 + q)];

    float o[4][4];   // [mt][r]: chan = mt*16 + q*4 + r, this lane's node
    float c2 = c2v[node];
    #pragma unroll
    for (int mt = 0; mt < 4; ++mt) {
        bf16x8 w2f[4];
        #pragma unroll
        for (int k4 = 0; k4 < 4; ++k4)
            w2f[k4] = *(const bf16x8*)&wimg[2048 + (k4 * 4 + q) * 64 + (mt * 16 + lm)];
        f32x4 a2 = (f32x4){0.f, 0.f, 0.f, 0.f};
        #pragma unroll
        for (int k4 = 0; k4 < 4; ++k4)
            a2 = __builtin_amdgcn_mfma_f32_16x16x32_bf16(w2f[k4], hf[k4], a2, 0, 0, 0);
        float4 bb = *(const float4*)(b2g + mt * 16 + q * 4);
        o[mt][0] = fmaf(c2, a2[0], bb.x);
        o[mt][1] = fmaf(c2, a2[1], bb.y);
        o[mt][2] = fmaf(c2, a2[2], bb.z);
        o[mt][3] = fmaf(c2, a2[3], bb.w);
    }

    // ---- in-register log-softmax over 64 chans (16 in-lane x 4 quads) ----
    float M = -1e30f;
    #pragma unroll
    for (int mt = 0; mt < 4; ++mt)
        #pragma unroll
        for (int r = 0; r < 4; ++r) M = fmaxf(M, o[mt][r]);
    M = fmaxf(M, __shfl_xor(M, 16));
    M = fmaxf(M, __shfl_xor(M, 32));

    float S = 0.f;
    #pragma unroll
    for (int mt = 0; mt < 4; ++mt)
        #pragma unroll
        for (int r = 0; r < 4; ++r) S += __expf(o[mt][r] - M);
    S += __shfl_xor(S, 16);
    S += __shfl_xor(S, 32);
    float lse = M + __logf(S);

    if (gn < NN) {
        #pragma unroll
        for (int mt = 0; mt < 4; ++mt) {
            float4 v;
            v.x = o[mt][0] - lse;
            v.y = o[mt][1] - lse;
            v.z = o[mt][2] - lse;
            v.w = o[mt][3] - lse;
            *(float4*)(out + (size_t)gn * COUT + mt * 16 + q * 4) = v;
        }
    }
}

extern "C" void kernel_launch(void* const* d_in, const int* in_sizes, int n_in,
                              void* d_out, int out_size, void* d_ws, size_t ws_size,
                              hipStream_t stream) {
    const float* x   = (const float*)d_in[0];
    // d_in[1] = neighbors — mathematically irrelevant (Re(G[0,j>=1]) == 0)
    const int* mask  = (const int*)d_in[2];
    const float* w1  = (const float*)d_in[3];
    const float* b1  = (const float*)d_in[4];
    const float* w2  = (const float*)d_in[5];
    const float* b2  = (const float*)d_in[6];
    float* out = (float*)d_out;

    uint4* wimg = (uint4*)d_ws;

    hipLaunchKernelGGL(wprep, dim3(12), dim3(BLOCK), 0, stream, w1, w2, wimg);

    int grid = (NN + TM - 1) / TM;   // 782
    hipLaunchKernelGGL(gcn_mfma, dim3(grid), dim3(BLOCK), 0, stream,
                       x, wimg, mask, b1, b2, out);
}